// Round 6
// baseline (542.666 us; speedup 1.0000x reference)
//
#include <hip/hip_runtime.h>

#define HD 128   // hidden / feature dim
#define PS 32    // pooling chunks per graph

// ---------------- init: zero counters, init graph ranges ----------------
__global__ __launch_bounds__(256) void k_init(int* cnt, int* cursor, int* gstart, int* gend, int n, int g) {
  int i = blockIdx.x * 256 + threadIdx.x;
  if (i < n) { cnt[i] = 0; cursor[i] = 0; }
  if (i < g) { gstart[i] = 0x7fffffff; gend[i] = -1; }
}

// ---------------- in-degree histogram over dst ----------------
__global__ __launch_bounds__(256) void k_hist(const int* __restrict__ dst, int* __restrict__ cnt, int e) {
  int i = blockIdx.x * 256 + threadIdx.x;
  if (i < e) atomicAdd(&cnt[dst[i]], 1);
}

// ---------------- exclusive scan (3 kernels) ----------------
__global__ __launch_bounds__(256) void k_scan1(const int* __restrict__ cnt, int* __restrict__ excl,
                                               int* __restrict__ bsum, int n) {
  __shared__ int s[256];
  int tid = threadIdx.x;
  int i = blockIdx.x * 256 + tid;
  int v = (i < n) ? cnt[i] : 0;
  s[tid] = v; __syncthreads();
  for (int off = 1; off < 256; off <<= 1) {
    int t = (tid >= off) ? s[tid - off] : 0;
    __syncthreads();
    s[tid] += t;
    __syncthreads();
  }
  if (i < n) excl[i] = s[tid] - v;
  if (tid == 255) bsum[blockIdx.x] = s[255];
}

__global__ __launch_bounds__(256) void k_scan2(int* __restrict__ bsum, int nb) {
  __shared__ int s[256];
  int tid = threadIdx.x;
  int v = (tid < nb) ? bsum[tid] : 0;
  s[tid] = v; __syncthreads();
  for (int off = 1; off < 256; off <<= 1) {
    int t = (tid >= off) ? s[tid - off] : 0;
    __syncthreads();
    s[tid] += t;
    __syncthreads();
  }
  if (tid < nb) bsum[tid] = s[tid] - v;
}

// rowptr += block offset; dis = rsqrt(1+deg_in); graph ranges via sorted-batch
// boundary detection (batch is sorted -> each graph is a contiguous node range)
__global__ __launch_bounds__(256) void k_finalize(int* __restrict__ rowptr, const int* __restrict__ bsum,
                                                  const int* __restrict__ cnt, float* __restrict__ dis,
                                                  const int* __restrict__ batch, int* __restrict__ gstart,
                                                  int* __restrict__ gend, int n) {
  int i = blockIdx.x * 256 + threadIdx.x;
  if (i >= n) return;
  rowptr[i] += bsum[blockIdx.x];
  dis[i] = rsqrtf(1.0f + (float)cnt[i]);
  int b = batch[i];
  if (i == 0 || batch[i - 1] != b) gstart[b] = i;       // plain stores, no atomics
  if (i == n - 1 || batch[i + 1] != b) gend[b] = i;
}

// ---------------- CSR fill: csr[rowptr[dst]+k] = src ----------------
__global__ __launch_bounds__(256) void k_fill(const int* __restrict__ src, const int* __restrict__ dst,
                                              const int* __restrict__ rowptr, int* __restrict__ cursor,
                                              int* __restrict__ csr, int e) {
  int i = blockIdx.x * 256 + threadIdx.x;
  if (i >= e) return;
  int d = dst[i];
  int pos = rowptr[d] + atomicAdd(&cursor[d], 1);
  csr[pos] = src[i];
}

// ---------------- fp32 GEMM: C[M x 128] = rowscale[r] * (A[M x 128] @ W[128 x 128]) --------
// block 256 threads, BM=64, BN=128, k-tile 32; per-thread 4x8 micro-tile
__global__ __launch_bounds__(256) void k_gemm(const float* __restrict__ A, const float* __restrict__ W,
                                              const float* __restrict__ rowscale,
                                              float* __restrict__ C, int M) {
  __shared__ float As[64 * 36];   // stride 36 keeps 16B alignment + spreads banks
  __shared__ float Ws[32 * 128];
  int tid = threadIdx.x;
  int tx = tid & 15, ty = tid >> 4;
  int row0 = blockIdx.x * 64;
  float acc[4][8];
#pragma unroll
  for (int i = 0; i < 4; ++i)
#pragma unroll
    for (int j = 0; j < 8; ++j) acc[i][j] = 0.f;

  for (int kt = 0; kt < HD; kt += 32) {
    __syncthreads();
#pragma unroll
    for (int u = 0; u < 2; ++u) {
      int s = u * 256 + tid;
      int r = s >> 3, kk = (s & 7) << 2;
      float4 v = make_float4(0.f, 0.f, 0.f, 0.f);
      if (row0 + r < M) v = *(const float4*)(A + (size_t)(row0 + r) * HD + kt + kk);
      *(float4*)(&As[r * 36 + kk]) = v;
    }
#pragma unroll
    for (int u = 0; u < 4; ++u) {
      int s = u * 256 + tid;
      int kr = s >> 5, c4 = (s & 31) << 2;
      *(float4*)(&Ws[kr * HD + c4]) = *(const float4*)(W + (size_t)(kt + kr) * HD + c4);
    }
    __syncthreads();
#pragma unroll
    for (int kk = 0; kk < 32; ++kk) {
      float4 blo = *(const float4*)(&Ws[kk * HD + tx * 8]);
      float4 bhi = *(const float4*)(&Ws[kk * HD + tx * 8 + 4]);
#pragma unroll
      for (int i = 0; i < 4; ++i) {
        float a = As[(ty * 4 + i) * 36 + kk];
        acc[i][0] += a * blo.x; acc[i][1] += a * blo.y;
        acc[i][2] += a * blo.z; acc[i][3] += a * blo.w;
        acc[i][4] += a * bhi.x; acc[i][5] += a * bhi.y;
        acc[i][6] += a * bhi.z; acc[i][7] += a * bhi.w;
      }
    }
  }
#pragma unroll
  for (int i = 0; i < 4; ++i) {
    int r = row0 + ty * 4 + i;
    if (r < M) {
      float sc = rowscale[r];
      *(float4*)(C + (size_t)r * HD + tx * 8) =
          make_float4(sc * acc[i][0], sc * acc[i][1], sc * acc[i][2], sc * acc[i][3]);
      *(float4*)(C + (size_t)r * HD + tx * 8 + 4) =
          make_float4(sc * acc[i][4], sc * acc[i][5], sc * acc[i][6], sc * acc[i][7]);
    }
  }
}

// ---------------- gather aggregation + self loop + bias + relu ----------------
// Channel-sliced, XCD-local: slice = blockIdx & 7 (round-robin XCD dispatch ->
// all blocks of one slice share an XCD; per-XCD feature slice = N*16*4B = 3.2MB
// fits the 4MB L2). C rows are pre-scaled by dis[row].
// Wave layout: 16 parallel edge-groups x 4 lanes (float4 = 16 channels/slice).
__global__ __launch_bounds__(256) void k_gather(const float* __restrict__ C, const float* __restrict__ dis,
                                                const int* __restrict__ rowptr, const int* __restrict__ cnt,
                                                const int* __restrict__ csr, const float* __restrict__ bias,
                                                float* __restrict__ out, int n) {
  int bid = blockIdx.x;
  int slice = bid & 7;                 // -> XCD under round-robin dispatch
  int chunk = bid >> 3;
  int lane = threadIdx.x & 63;
  int wid = threadIdx.x >> 6;
  int eg = lane >> 2;                  // edge-group 0..15
  int cl = lane & 3;                   // channel-quad 0..3
  int coff = slice * 16 + cl * 4;      // this lane's 4 channels

  float4 bb = *(const float4*)(bias + coff);

  const int NPW = 4;                   // nodes per wave (sequential)
  int node0 = (chunk * 4 + wid) * NPW;
#pragma unroll
  for (int u = 0; u < NPW; ++u) {
    int node = node0 + u;
    if (node >= n) return;
    int base = rowptr[node];
    int deg = cnt[node];
    float dn = dis[node];
    float4 selfv = *(const float4*)(C + (size_t)node * HD + coff);

    float4 acc = make_float4(0.f, 0.f, 0.f, 0.f);
    for (int i = eg; i < deg; i += 16) {
      int idx = csr[base + i];
      float4 v = *(const float4*)(C + (size_t)idx * HD + coff);
      acc.x += v.x; acc.y += v.y; acc.z += v.z; acc.w += v.w;
    }
    // reduce over the 16 edge-groups (lane bits 2..5)
#pragma unroll
    for (int m = 4; m <= 32; m <<= 1) {
      acc.x += __shfl_xor(acc.x, m);
      acc.y += __shfl_xor(acc.y, m);
      acc.z += __shfl_xor(acc.z, m);
      acc.w += __shfl_xor(acc.w, m);
    }
    if (eg == 0) {
      float4 r;
      r.x = fmaxf(dn * (acc.x + selfv.x) + bb.x, 0.f);
      r.y = fmaxf(dn * (acc.y + selfv.y) + bb.y, 0.f);
      r.z = fmaxf(dn * (acc.z + selfv.z) + bb.z, 0.f);
      r.w = fmaxf(dn * (acc.w + selfv.w) + bb.w, 0.f);
      *(float4*)(out + (size_t)node * HD + coff) = r;
    }
  }
}

// ---------------- pooling stage 1: per-(graph, chunk) partial sum+max ----------------
__global__ __launch_bounds__(128) void k_pool1(const float* __restrict__ h, const int* __restrict__ gstart,
                                               const int* __restrict__ gend, float* __restrict__ psum,
                                               float* __restrict__ pmax) {
  int g = blockIdx.x, sidx = blockIdx.y, c = threadIdx.x;
  int s = gstart[g], e = gend[g];
  float sum = 0.f, mx = 0.f;        // h >= 0 post-ReLU, so 0 is a safe max identity
  if (s <= e) {
    int len = e - s + 1;
    int c0 = s + (int)(((long long)len * sidx) / PS);
    int c1 = s + (int)(((long long)len * (sidx + 1)) / PS);
    for (int i = c0; i < c1; ++i) {
      float v = h[(size_t)i * HD + c];
      sum += v;
      mx = fmaxf(mx, v);
    }
  }
  size_t o = ((size_t)g * PS + sidx) * HD + c;
  psum[o] = sum;
  pmax[o] = mx;
}

// ---------------- pooling stage 2: combine partials, mean+max concat ----------------
__global__ __launch_bounds__(128) void k_pool2(const float* __restrict__ psum, const float* __restrict__ pmax,
                                               const int* __restrict__ gstart, const int* __restrict__ gend,
                                               float* __restrict__ pooled) {
  int g = blockIdx.x, c = threadIdx.x;
  float sum = 0.f, mx = 0.f;
  for (int sidx = 0; sidx < PS; ++sidx) {
    size_t o = ((size_t)g * PS + sidx) * HD + c;
    sum += psum[o];
    mx = fmaxf(mx, pmax[o]);
  }
  int s = gstart[g], e = gend[g];
  float cntf = (s <= e) ? (float)(e - s + 1) : 1.0f;
  pooled[g * 256 + c] = sum / cntf;
  pooled[g * 256 + 128 + c] = mx;
}

// ---------------- final MLP: relu(pooled @ Wf1 + bf1) @ Wf2 + bf2 ----------------
__global__ __launch_bounds__(128) void k_mlp(const float* __restrict__ pooled, const float* __restrict__ Wf1,
                                             const float* __restrict__ bf1, const float* __restrict__ Wf2,
                                             const float* __restrict__ bf2, float* __restrict__ out) {
  __shared__ float p[256];
  __shared__ float red[128];
  int g = blockIdx.x, t = threadIdx.x;
  p[t] = pooled[g * 256 + t];
  p[t + 128] = pooled[g * 256 + 128 + t];
  __syncthreads();
  float acc = bf1[t];
  for (int k = 0; k < 256; ++k) acc += p[k] * Wf1[k * HD + t];
  float hv = fmaxf(acc, 0.f);
  red[t] = hv * Wf2[t];
  __syncthreads();
  for (int off = 64; off > 0; off >>= 1) {
    if (t < off) red[t] += red[t + off];
    __syncthreads();
  }
  if (t == 0) out[g] = red[0] + bf2[0];
}

extern "C" void kernel_launch(void* const* d_in, const int* in_sizes, int n_in,
                              void* d_out, int out_size, void* d_ws, size_t ws_size,
                              hipStream_t stream) {
  const float* x   = (const float*)d_in[0];
  const int*   ei  = (const int*)d_in[1];
  const int*   bat = (const int*)d_in[2];
  const float* W1  = (const float*)d_in[3];
  const float* b1  = (const float*)d_in[4];
  const float* W2  = (const float*)d_in[5];
  const float* b2  = (const float*)d_in[6];
  const float* W3  = (const float*)d_in[7];
  const float* b3  = (const float*)d_in[8];
  const float* Wf1 = (const float*)d_in[9];
  const float* bf1 = (const float*)d_in[10];
  const float* Wf2 = (const float*)d_in[11];
  const float* bf2 = (const float*)d_in[12];

  int N = in_sizes[0] / HD;
  int E = in_sizes[1] / 2;
  int G = out_size;

  char* w = (char*)d_ws;
  size_t off = 0;
  auto alloc = [&](size_t bytes) -> void* {
    void* p = w + off;
    off = (off + bytes + 255) & ~(size_t)255;
    return p;
  };
  float* bufA   = (float*)alloc((size_t)N * HD * 4);
  float* bufB   = (float*)alloc((size_t)N * HD * 4);
  int*   csr    = (int*)alloc((size_t)E * 4);
  int*   cnt    = (int*)alloc((size_t)N * 4);
  int*   rowptr = (int*)alloc((size_t)N * 4);
  int*   cursor = (int*)alloc((size_t)N * 4);
  float* dis    = (float*)alloc((size_t)N * 4);
  int*   bsum   = (int*)alloc(256 * 4);
  int*   gstart = (int*)alloc((size_t)G * 4);
  int*   gend   = (int*)alloc((size_t)G * 4);
  float* pooled = (float*)alloc((size_t)G * 256 * 4);
  float* psum   = (float*)alloc((size_t)G * PS * HD * 4);
  float* pmax   = (float*)alloc((size_t)G * PS * HD * 4);

  int nbN = (N + 255) / 256;
  int nbE = (E + 255) / 256;

  k_init<<<nbN, 256, 0, stream>>>(cnt, cursor, gstart, gend, N, G);
  k_hist<<<nbE, 256, 0, stream>>>(ei + E, cnt, E);
  k_scan1<<<nbN, 256, 0, stream>>>(cnt, rowptr, bsum, N);
  k_scan2<<<1, 256, 0, stream>>>(bsum, nbN);
  k_finalize<<<nbN, 256, 0, stream>>>(rowptr, bsum, cnt, dis, bat, gstart, gend, N);
  k_fill<<<nbE, 256, 0, stream>>>(ei, ei + E, rowptr, cursor, csr, E);

  int gb = (N + 63) / 64;
  // gather: 16 nodes per block (4 waves x 4 nodes), x8 channel slices
  int ab = 8 * ((N + 15) / 16);
  k_gemm<<<gb, 256, 0, stream>>>(x, W1, dis, bufA, N);
  k_gather<<<ab, 256, 0, stream>>>(bufA, dis, rowptr, cnt, csr, b1, bufB, N);
  k_gemm<<<gb, 256, 0, stream>>>(bufB, W2, dis, bufA, N);
  k_gather<<<ab, 256, 0, stream>>>(bufA, dis, rowptr, cnt, csr, b2, bufB, N);
  k_gemm<<<gb, 256, 0, stream>>>(bufB, W3, dis, bufA, N);
  k_gather<<<ab, 256, 0, stream>>>(bufA, dis, rowptr, cnt, csr, b3, bufB, N);

  dim3 pgrid(G, PS);
  k_pool1<<<pgrid, 128, 0, stream>>>(bufB, gstart, gend, psum, pmax);
  k_pool2<<<G, 128, 0, stream>>>(psum, pmax, gstart, gend, pooled);
  k_mlp<<<G, 128, 0, stream>>>(pooled, Wf1, bf1, Wf2, bf2, (float*)d_out);
}

// Round 7
// 372.400 us; speedup vs baseline: 1.4572x; 1.4572x over previous
//
#include <hip/hip_runtime.h>

#define HD 128   // hidden / feature dim
#define PS 32    // pooling chunks per graph

// ---------------- init: zero counters, init graph ranges ----------------
__global__ __launch_bounds__(256) void k_init(int* cnt, int* cursor, int* gstart, int* gend, int n, int g) {
  int i = blockIdx.x * 256 + threadIdx.x;
  if (i < n) { cnt[i] = 0; cursor[i] = 0; }
  if (i < g) { gstart[i] = 0x7fffffff; gend[i] = -1; }
}

// ---------------- in-degree histogram over dst ----------------
__global__ __launch_bounds__(256) void k_hist(const int* __restrict__ dst, int* __restrict__ cnt, int e) {
  int i = blockIdx.x * 256 + threadIdx.x;
  if (i < e) atomicAdd(&cnt[dst[i]], 1);
}

// ---------------- exclusive scan (3 kernels) ----------------
__global__ __launch_bounds__(256) void k_scan1(const int* __restrict__ cnt, int* __restrict__ excl,
                                               int* __restrict__ bsum, int n) {
  __shared__ int s[256];
  int tid = threadIdx.x;
  int i = blockIdx.x * 256 + tid;
  int v = (i < n) ? cnt[i] : 0;
  s[tid] = v; __syncthreads();
  for (int off = 1; off < 256; off <<= 1) {
    int t = (tid >= off) ? s[tid - off] : 0;
    __syncthreads();
    s[tid] += t;
    __syncthreads();
  }
  if (i < n) excl[i] = s[tid] - v;
  if (tid == 255) bsum[blockIdx.x] = s[255];
}

__global__ __launch_bounds__(256) void k_scan2(int* __restrict__ bsum, int nb) {
  __shared__ int s[256];
  int tid = threadIdx.x;
  int v = (tid < nb) ? bsum[tid] : 0;
  s[tid] = v; __syncthreads();
  for (int off = 1; off < 256; off <<= 1) {
    int t = (tid >= off) ? s[tid - off] : 0;
    __syncthreads();
    s[tid] += t;
    __syncthreads();
  }
  if (tid < nb) bsum[tid] = s[tid] - v;
}

// rowptr += block offset; dis = rsqrt(1+deg_in); graph ranges via sorted-batch
// boundary detection (batch is sorted -> each graph is a contiguous node range)
__global__ __launch_bounds__(256) void k_finalize(int* __restrict__ rowptr, const int* __restrict__ bsum,
                                                  const int* __restrict__ cnt, float* __restrict__ dis,
                                                  const int* __restrict__ batch, int* __restrict__ gstart,
                                                  int* __restrict__ gend, int n) {
  int i = blockIdx.x * 256 + threadIdx.x;
  if (i >= n) return;
  rowptr[i] += bsum[blockIdx.x];
  dis[i] = rsqrtf(1.0f + (float)cnt[i]);
  int b = batch[i];
  if (i == 0 || batch[i - 1] != b) gstart[b] = i;       // plain stores, no atomics
  if (i == n - 1 || batch[i + 1] != b) gend[b] = i;
}

// ---------------- CSR fill: csr[rowptr[dst]+k] = src ----------------
__global__ __launch_bounds__(256) void k_fill(const int* __restrict__ src, const int* __restrict__ dst,
                                              const int* __restrict__ rowptr, int* __restrict__ cursor,
                                              int* __restrict__ csr, int e) {
  int i = blockIdx.x * 256 + threadIdx.x;
  if (i >= e) return;
  int d = dst[i];
  int pos = rowptr[d] + atomicAdd(&cursor[d], 1);
  csr[pos] = src[i];
}

// ---------------- fp32 GEMM: C[M x 128] = rowscale[r] * (A[M x 128] @ W[128 x 128]) --------
// BM=128, BN=64, BK=32; 256 threads; micro-tile 8x4.
// A staged k-major (transposed) in LDS -> A-side reads are 2 broadcast b128s;
// B-side 1 conflict-free b128. 3 b128 per 32 wave-FMA-instructions: VALU-bound.
#define GBM 128
#define GBN 64
#define GBK 32
__global__ __launch_bounds__(256) void k_gemm(const float* __restrict__ A, const float* __restrict__ W,
                                              const float* __restrict__ rowscale,
                                              float* __restrict__ C, int M) {
  __shared__ float As[GBK][GBM + 4];   // k-major; stride 132 floats = 528B (16B-aligned)
  __shared__ float Ws[GBK][GBN + 4];   // stride 68 floats = 272B (16B-aligned)
  int tid = threadIdx.x;
  int tx = tid & 15;                   // cols tx*4..+4
  int ty = tid >> 4;                   // rows ty*8..+8
  int row0 = blockIdx.x * GBM;
  int col0 = blockIdx.y * GBN;
  float acc[8][4];
#pragma unroll
  for (int i = 0; i < 8; ++i)
#pragma unroll
    for (int j = 0; j < 4; ++j) acc[i][j] = 0.f;

  for (int kt = 0; kt < HD; kt += GBK) {
    __syncthreads();
    // A tile: 128 rows x 32 k = 1024 float4, 4 per thread; store transposed
#pragma unroll
    for (int u = 0; u < 4; ++u) {
      int flat = u * 256 + tid;
      int r = flat >> 3;               // 8 float4 per row
      int kq = (flat & 7) << 2;
      float4 v = make_float4(0.f, 0.f, 0.f, 0.f);
      if (row0 + r < M) v = *(const float4*)(A + (size_t)(row0 + r) * HD + kt + kq);
      As[kq + 0][r] = v.x; As[kq + 1][r] = v.y; As[kq + 2][r] = v.z; As[kq + 3][r] = v.w;
    }
    // W tile: 32 k x 64 cols = 512 float4, 2 per thread, row-major
#pragma unroll
    for (int u = 0; u < 2; ++u) {
      int flat = u * 256 + tid;
      int kr = flat >> 4;              // 16 float4 per row
      int c4 = (flat & 15) << 2;
      *(float4*)(&Ws[kr][c4]) = *(const float4*)(W + (size_t)(kt + kr) * HD + col0 + c4);
    }
    __syncthreads();
#pragma unroll
    for (int kk = 0; kk < GBK; ++kk) {
      float4 b = *(const float4*)(&Ws[kk][tx * 4]);
      float4 alo = *(const float4*)(&As[kk][ty * 8]);
      float4 ahi = *(const float4*)(&As[kk][ty * 8 + 4]);
      float ar[8] = {alo.x, alo.y, alo.z, alo.w, ahi.x, ahi.y, ahi.z, ahi.w};
#pragma unroll
      for (int i = 0; i < 8; ++i) {
        acc[i][0] += ar[i] * b.x; acc[i][1] += ar[i] * b.y;
        acc[i][2] += ar[i] * b.z; acc[i][3] += ar[i] * b.w;
      }
    }
  }
#pragma unroll
  for (int i = 0; i < 8; ++i) {
    int r = row0 + ty * 8 + i;
    if (r < M) {
      float sc = rowscale[r];
      *(float4*)(C + (size_t)r * HD + col0 + tx * 4) =
          make_float4(sc * acc[i][0], sc * acc[i][1], sc * acc[i][2], sc * acc[i][3]);
    }
  }
}

// ---------------- gather aggregation + self loop + bias + relu ----------------
// C rows are pre-scaled by dis[row]. out = relu(dn*(sum C[src] + C[node]) + b).
// One wave per node; half-wave 0 (lanes 0-31) takes even edge slots, half 1 odd.
// Each lane covers 4 channels (float4), so one dwordx4 wave-load = 2 rows.
__global__ __launch_bounds__(256) void k_gather(const float* __restrict__ C, const float* __restrict__ dis,
                                                const int* __restrict__ rowptr, const int* __restrict__ cnt,
                                                const int* __restrict__ csr, const float* __restrict__ bias,
                                                float* __restrict__ out, int n) {
  int lane = threadIdx.x & 63;
  int wid = threadIdx.x >> 6;
  int node = blockIdx.x * 4 + wid;
  if (node >= n) return;
  int half = lane >> 5;          // 0 or 1
  int l32 = lane & 31;
  int coff = l32 * 4;            // this lane's 4 channels
  int s = rowptr[node];
  int deg = cnt[node];

  float dn = dis[node];
  float4 selfv = *(const float4*)(C + (size_t)node * HD + coff);
  float4 bb = *(const float4*)(bias + coff);

  float4 a0 = make_float4(0.f, 0.f, 0.f, 0.f);
  float4 a1 = make_float4(0.f, 0.f, 0.f, 0.f);
  int i = 0;
  for (; i + 4 <= deg; i += 4) {           // 4 edges/iter: half h takes slots i+h, i+2+h
    int i0 = csr[s + i + half];
    int i1 = csr[s + i + 2 + half];
    float4 v0 = *(const float4*)(C + (size_t)i0 * HD + coff);
    float4 v1 = *(const float4*)(C + (size_t)i1 * HD + coff);
    a0.x += v0.x; a0.y += v0.y; a0.z += v0.z; a0.w += v0.w;
    a1.x += v1.x; a1.y += v1.y; a1.z += v1.z; a1.w += v1.w;
  }
  if (i + 2 <= deg) {                      // 2 edges: half h takes slot i+h
    int i0 = csr[s + i + half];
    float4 v0 = *(const float4*)(C + (size_t)i0 * HD + coff);
    a0.x += v0.x; a0.y += v0.y; a0.z += v0.z; a0.w += v0.w;
    i += 2;
  }
  if (i < deg && half == 0) {              // last edge: half 0 only
    int i0 = csr[s + i];
    float4 v0 = *(const float4*)(C + (size_t)i0 * HD + coff);
    a0.x += v0.x; a0.y += v0.y; a0.z += v0.z; a0.w += v0.w;
  }
  a0.x += a1.x; a0.y += a1.y; a0.z += a1.z; a0.w += a1.w;
  // combine the two half-wave partials (lane <-> lane^32)
  a0.x += __shfl_xor(a0.x, 32);
  a0.y += __shfl_xor(a0.y, 32);
  a0.z += __shfl_xor(a0.z, 32);
  a0.w += __shfl_xor(a0.w, 32);

  if (half == 0) {
    float4 r;
    r.x = fmaxf(dn * (a0.x + selfv.x) + bb.x, 0.f);
    r.y = fmaxf(dn * (a0.y + selfv.y) + bb.y, 0.f);
    r.z = fmaxf(dn * (a0.z + selfv.z) + bb.z, 0.f);
    r.w = fmaxf(dn * (a0.w + selfv.w) + bb.w, 0.f);
    *(float4*)(out + (size_t)node * HD + coff) = r;
  }
}

// ---------------- pooling stage 1: per-(graph, chunk) partial sum+max ----------------
__global__ __launch_bounds__(128) void k_pool1(const float* __restrict__ h, const int* __restrict__ gstart,
                                               const int* __restrict__ gend, float* __restrict__ psum,
                                               float* __restrict__ pmax) {
  int g = blockIdx.x, sidx = blockIdx.y, c = threadIdx.x;
  int s = gstart[g], e = gend[g];
  float sum = 0.f, mx = 0.f;        // h >= 0 post-ReLU, so 0 is a safe max identity
  if (s <= e) {
    int len = e - s + 1;
    int c0 = s + (int)(((long long)len * sidx) / PS);
    int c1 = s + (int)(((long long)len * (sidx + 1)) / PS);
    for (int i = c0; i < c1; ++i) {
      float v = h[(size_t)i * HD + c];
      sum += v;
      mx = fmaxf(mx, v);
    }
  }
  size_t o = ((size_t)g * PS + sidx) * HD + c;
  psum[o] = sum;
  pmax[o] = mx;
}

// ---------------- pooling stage 2: combine partials, mean+max concat ----------------
__global__ __launch_bounds__(128) void k_pool2(const float* __restrict__ psum, const float* __restrict__ pmax,
                                               const int* __restrict__ gstart, const int* __restrict__ gend,
                                               float* __restrict__ pooled) {
  int g = blockIdx.x, c = threadIdx.x;
  float sum = 0.f, mx = 0.f;
  for (int sidx = 0; sidx < PS; ++sidx) {
    size_t o = ((size_t)g * PS + sidx) * HD + c;
    sum += psum[o];
    mx = fmaxf(mx, pmax[o]);
  }
  int s = gstart[g], e = gend[g];
  float cntf = (s <= e) ? (float)(e - s + 1) : 1.0f;
  pooled[g * 256 + c] = sum / cntf;
  pooled[g * 256 + 128 + c] = mx;
}

// ---------------- final MLP: relu(pooled @ Wf1 + bf1) @ Wf2 + bf2 ----------------
__global__ __launch_bounds__(128) void k_mlp(const float* __restrict__ pooled, const float* __restrict__ Wf1,
                                             const float* __restrict__ bf1, const float* __restrict__ Wf2,
                                             const float* __restrict__ bf2, float* __restrict__ out) {
  __shared__ float p[256];
  __shared__ float red[128];
  int g = blockIdx.x, t = threadIdx.x;
  p[t] = pooled[g * 256 + t];
  p[t + 128] = pooled[g * 256 + 128 + t];
  __syncthreads();
  float acc = bf1[t];
  for (int k = 0; k < 256; ++k) acc += p[k] * Wf1[k * HD + t];
  float hv = fmaxf(acc, 0.f);
  red[t] = hv * Wf2[t];
  __syncthreads();
  for (int off = 64; off > 0; off >>= 1) {
    if (t < off) red[t] += red[t + off];
    __syncthreads();
  }
  if (t == 0) out[g] = red[0] + bf2[0];
}

extern "C" void kernel_launch(void* const* d_in, const int* in_sizes, int n_in,
                              void* d_out, int out_size, void* d_ws, size_t ws_size,
                              hipStream_t stream) {
  const float* x   = (const float*)d_in[0];
  const int*   ei  = (const int*)d_in[1];
  const int*   bat = (const int*)d_in[2];
  const float* W1  = (const float*)d_in[3];
  const float* b1  = (const float*)d_in[4];
  const float* W2  = (const float*)d_in[5];
  const float* b2  = (const float*)d_in[6];
  const float* W3  = (const float*)d_in[7];
  const float* b3  = (const float*)d_in[8];
  const float* Wf1 = (const float*)d_in[9];
  const float* bf1 = (const float*)d_in[10];
  const float* Wf2 = (const float*)d_in[11];
  const float* bf2 = (const float*)d_in[12];

  int N = in_sizes[0] / HD;
  int E = in_sizes[1] / 2;
  int G = out_size;

  char* w = (char*)d_ws;
  size_t off = 0;
  auto alloc = [&](size_t bytes) -> void* {
    void* p = w + off;
    off = (off + bytes + 255) & ~(size_t)255;
    return p;
  };
  float* bufA   = (float*)alloc((size_t)N * HD * 4);
  float* bufB   = (float*)alloc((size_t)N * HD * 4);
  int*   csr    = (int*)alloc((size_t)E * 4);
  int*   cnt    = (int*)alloc((size_t)N * 4);
  int*   rowptr = (int*)alloc((size_t)N * 4);
  int*   cursor = (int*)alloc((size_t)N * 4);
  float* dis    = (float*)alloc((size_t)N * 4);
  int*   bsum   = (int*)alloc(256 * 4);
  int*   gstart = (int*)alloc((size_t)G * 4);
  int*   gend   = (int*)alloc((size_t)G * 4);
  float* pooled = (float*)alloc((size_t)G * 256 * 4);
  float* psum   = (float*)alloc((size_t)G * PS * HD * 4);
  float* pmax   = (float*)alloc((size_t)G * PS * HD * 4);

  int nbN = (N + 255) / 256;
  int nbE = (E + 255) / 256;

  k_init<<<nbN, 256, 0, stream>>>(cnt, cursor, gstart, gend, N, G);
  k_hist<<<nbE, 256, 0, stream>>>(ei + E, cnt, E);
  k_scan1<<<nbN, 256, 0, stream>>>(cnt, rowptr, bsum, N);
  k_scan2<<<1, 256, 0, stream>>>(bsum, nbN);
  k_finalize<<<nbN, 256, 0, stream>>>(rowptr, bsum, cnt, dis, bat, gstart, gend, N);
  k_fill<<<nbE, 256, 0, stream>>>(ei, ei + E, rowptr, cursor, csr, E);

  dim3 ggrid((N + GBM - 1) / GBM, HD / GBN);
  int ab = (N + 3) / 4;
  k_gemm<<<ggrid, 256, 0, stream>>>(x, W1, dis, bufA, N);
  k_gather<<<ab, 256, 0, stream>>>(bufA, dis, rowptr, cnt, csr, b1, bufB, N);
  k_gemm<<<ggrid, 256, 0, stream>>>(bufB, W2, dis, bufA, N);
  k_gather<<<ab, 256, 0, stream>>>(bufA, dis, rowptr, cnt, csr, b2, bufB, N);
  k_gemm<<<ggrid, 256, 0, stream>>>(bufB, W3, dis, bufA, N);
  k_gather<<<ab, 256, 0, stream>>>(bufA, dis, rowptr, cnt, csr, b3, bufB, N);

  dim3 pgrid(G, PS);
  k_pool1<<<pgrid, 128, 0, stream>>>(bufB, gstart, gend, psum, pmax);
  k_pool2<<<G, 128, 0, stream>>>(psum, pmax, gstart, gend, pooled);
  k_mlp<<<G, 128, 0, stream>>>(pooled, Wf1, bf1, Wf2, bf2, (float*)d_out);
}